// Round 1
// baseline (81.602 us; speedup 1.0000x reference)
//
#include <hip/hip_runtime.h>
#include <hip/hip_bf16.h>

// EmbeddingMul2: out[b,s,:] = embedding[input_[b,s], :]
// input_:    (8, 256) int32   -> 2048 indices in [0, 50000)
// embedding: (50000, 256) fp32
// out:       (8, 256, 256) fp32 = 524288 floats = 2 MiB
//
// Pure gather. One wave (64 lanes) copies one 256-float row via float4
// (16 B/lane * 64 lanes = 1024 B = one full row per vector load+store).
// Block = 256 threads = 4 rows; grid = 2048/4 = 512 blocks.

#define NUM_DIMS 256
#define NUM_ROWS 2048  // 8 * 256 indices

__global__ __launch_bounds__(256) void EmbeddingMul2_16183436772039_kernel(
    const int* __restrict__ idx,
    const float* __restrict__ emb,
    float* __restrict__ out) {
    int t = blockIdx.x * blockDim.x + threadIdx.x;  // 0 .. 131071
    int row  = t >> 6;   // 64 lanes per row (256 floats / 4 per lane)
    int col4 = t & 63;   // float4 index within the row

    int e = idx[row];  // wave-uniform per 64-lane group -> broadcast

    const float4* __restrict__ src = (const float4*)(emb + (size_t)e * NUM_DIMS);
    float4* __restrict__ dst       = (float4*)(out + (size_t)row * NUM_DIMS);
    dst[col4] = src[col4];
}

extern "C" void kernel_launch(void* const* d_in, const int* in_sizes, int n_in,
                              void* d_out, int out_size, void* d_ws, size_t ws_size,
                              hipStream_t stream) {
    const int*   idx = (const int*)d_in[0];    // input_  (8*256 int32)
    const float* emb = (const float*)d_in[1];  // embedding (50000*256 fp32)
    float*       out = (float*)d_out;          // (8,256,256) fp32

    // 2048 rows * 64 lanes/row = 131072 threads; 256/block -> 512 blocks
    dim3 grid(NUM_ROWS * 64 / 256);
    dim3 block(256);
    EmbeddingMul2_16183436772039_kernel<<<grid, block, 0, stream>>>(idx, emb, out);
}